// Round 4
// baseline (384.530 us; speedup 1.0000x reference)
//
#include <hip/hip_runtime.h>
#include <math.h>

#define N_ROWS 131072
#define DIM 1024
#define KNNK 32
#define NBIN 65536
#define LISTCAP 2048
typedef unsigned int u32;

// ws layout (u32 units):
//   kl      @ 0        (131072 floats)
//   hist    @ 131072   (2*65536 u32)
//   state   @ 262144   (16 u32)  [0..2]=B  [3..5]=CB  [6]=n_c0 [7]=n_c1 [8]=n_g
//                                [9]=S0(f) [10]=S1(f) [11]=n0_below
//   lv0     @ 262160   (2048 f)
//   lv1     @ 264208   (2048 f)
//   lgv     @ 266256   (2048 f)
//   lgc     @ 268304   (2048 u32)

__device__ __forceinline__ float wave_sum(float v) {
#pragma unroll
  for (int off = 32; off > 0; off >>= 1) v += __shfl_xor(v, off, 64);
  return v;
}
__device__ __forceinline__ int wave_sum_i(int v) {
#pragma unroll
  for (int off = 32; off > 0; off >>= 1) v += __shfl_xor(v, off, 64);
  return v;
}
__device__ __forceinline__ float sum4(float4 a) { return (a.x + a.y) + (a.z + a.w); }
__device__ __forceinline__ float4 sqdiff(float4 a, float m) {
  float4 r;
  r.x = (a.x - m) * (a.x - m);
  r.y = (a.y - m) * (a.y - m);
  r.z = (a.z - m) * (a.z - m);
  r.w = (a.w - m) * (a.w - m);
  return r;
}
__device__ __forceinline__ float acc4(float4 a, float4 m, float mean, float p) {
  float d;
  d = a.x - mean; p += fabsf(d * d - m.x);
  d = a.y - mean; p += fabsf(d * d - m.y);
  d = a.z - mean; p += fabsf(d * d - m.z);
  d = a.w - mean; p += fabsf(d * d - m.w);
  return p;
}

// ---- kernel 1: kl pass, rolling single-row register prefetch, 8 waves/SIMD.
// Also zeros hist+state (consumed only by later dispatches).
__global__ void __launch_bounds__(256) k_kl(const float* __restrict__ A,
                                            const float* __restrict__ q,
                                            float* __restrict__ kl,
                                            u32* __restrict__ zbase) {
  int t = threadIdx.x;
  u32 gid = blockIdx.x * 256 + t;
  if (gid < 2 * NBIN + 16) zbase[gid] = 0;   // hist + state

  int lane = t & 63;
  int gw = blockIdx.x * 4 + (t >> 6);        // wave id in [0, 8192)
  const int nw = 8192;

  const float4* Q4 = reinterpret_cast<const float4*>(q);
  float4 q0 = Q4[lane], q1 = Q4[64 + lane], q2 = Q4[128 + lane], q3 = Q4[192 + lane];
  float qs = sum4(q0) + sum4(q1) + sum4(q2) + sum4(q3);
  qs = wave_sum(qs);
  float qm = qs * (1.0f / DIM);
  float4 m0 = sqdiff(q0, qm), m1 = sqdiff(q1, qm),
         m2 = sqdiff(q2, qm), m3 = sqdiff(q3, qm);

  const float4* A4 = reinterpret_cast<const float4*>(A);
  size_t rb = (size_t)gw * 256;
  float4 c0 = A4[rb + lane], c1 = A4[rb + 64 + lane],
         c2 = A4[rb + 128 + lane], c3 = A4[rb + 192 + lane];

#pragma unroll 1
  for (int k = 0; k < 16; ++k) {
    int row = gw + k * nw;
    int nrow = min(row + nw, N_ROWS - 1);
    size_t nb = (size_t)nrow * 256;
    float4 n0 = A4[nb + lane], n1 = A4[nb + 64 + lane],
           n2 = A4[nb + 128 + lane], n3 = A4[nb + 192 + lane];

    float s = sum4(c0) + sum4(c1) + sum4(c2) + sum4(c3);
    s = wave_sum(s);
    float mean = s * (1.0f / DIM);
    float p = 0.0f;
    p = acc4(c0, m0, mean, p);
    p = acc4(c1, m1, mean, p);
    p = acc4(c2, m2, mean, p);
    p = acc4(c3, m3, mean, p);
    p = wave_sum(p);
    if (lane == 0) kl[row] = p;
    c0 = n0; c1 = n1; c2 = n2; c3 = n3;
  }
}

// ---- kernel 2: 16-bit-prefix histogram (positive floats: bits are monotone)
__global__ void __launch_bounds__(256) k_h16(const float* __restrict__ kl,
                                             const int* __restrict__ lab,
                                             u32* __restrict__ hist) {
  int i = blockIdx.x * 256 + threadIdx.x;  // 512 blocks -> exactly 131072
  u32 key = __float_as_uint(kl[i]) >> 16;
  int c = lab[i];
  atomicAdd(&hist[c * NBIN + key], 1u);
}

// ---- kernel 3: scan histograms, find bin + rank of 32nd smallest ----------
// selectors: 0 = class0, 1 = class1, 2 = union
__global__ void __launch_bounds__(1024) k_scan(const u32* __restrict__ hist,
                                               u32* __restrict__ state) {
  __shared__ u32 sc[1024];
  int t = threadIdx.x;
  for (int s = 0; s < 3; ++s) {
    u32 sum = 0;
    int base = t * 64;
    for (int k = 0; k < 64; ++k) {
      int i = base + k;
      u32 h = (s < 2) ? hist[s * NBIN + i] : hist[i] + hist[NBIN + i];
      sum += h;
    }
    sc[t] = sum;
    __syncthreads();
    for (int off = 1; off < 1024; off <<= 1) {
      u32 v = (t >= off) ? sc[t - off] : 0;
      __syncthreads();
      sc[t] += v;
      __syncthreads();
    }
    u32 excl = sc[t] - sum;
    u32 c0 = excl;
    for (int k = 0; k < 64; ++k) {
      int i = base + k;
      u32 h = (s < 2) ? hist[s * NBIN + i] : hist[i] + hist[NBIN + i];
      if (c0 < KNNK && c0 + h >= KNNK) {
        state[s] = (u32)i;      // bin containing the 32nd smallest
        state[3 + s] = c0;      // count strictly below that bin
      }
      c0 += h;
    }
    __syncthreads();
  }
}

// ---- kernel 4: collect below-bin sums + boundary-bin lists ----------------
__global__ void __launch_bounds__(256) k_collect(const float* __restrict__ kl,
                                                 const int* __restrict__ lab,
                                                 u32* __restrict__ state,
                                                 float* __restrict__ lv0,
                                                 float* __restrict__ lv1,
                                                 float* __restrict__ lgv,
                                                 u32* __restrict__ lgc) {
  int i = blockIdx.x * 256 + threadIdx.x;
  float v = kl[i];
  int c = lab[i];
  u32 key = __float_as_uint(v) >> 16;
  u32 Bc = state[c];
  u32 Bg = state[2];
  float* S = (float*)&state[9];
  if (key < Bc) {
    atomicAdd(&S[c], v);
  } else if (key == Bc) {
    u32 idx = atomicAdd(&state[6 + c], 1u);
    if (idx < LISTCAP) (c ? lv1 : lv0)[idx] = v;
  }
  if (key < Bg) {
    if (c == 0) atomicAdd(&state[11], 1u);
  } else if (key == Bg) {
    u32 idx = atomicAdd(&state[8], 1u);
    if (idx < LISTCAP) { lgv[idx] = v; lgc[idx] = (u32)c; }
  }
}

// ---- kernel 5: in-bin exact ranking, means, normalize, vote ---------------
__global__ void __launch_bounds__(256) k_finish(const float* __restrict__ lv0g,
                                                const float* __restrict__ lv1g,
                                                const float* __restrict__ lgvg,
                                                const u32* __restrict__ lgcg,
                                                const u32* __restrict__ state,
                                                float* __restrict__ out) {
  __shared__ float lv0[LISTCAP], lv1[LISTCAP], lgv[LISTCAP];
  __shared__ u32 lgc[LISTCAP];
  __shared__ float r_idm[2];
  __shared__ int r_n0;
  int t = threadIdx.x, wid = t >> 6, lane = t & 63;
  int m0 = min((int)state[6], LISTCAP);
  int m1 = min((int)state[7], LISTCAP);
  int mg = min((int)state[8], LISTCAP);
  if (wid == 0) for (int j = lane; j < m0; j += 64) lv0[j] = lv0g[j];
  if (wid == 1) for (int j = lane; j < m1; j += 64) lv1[j] = lv1g[j];
  if (wid == 2) for (int j = lane; j < mg; j += 64) { lgv[j] = lgvg[j]; lgc[j] = lgcg[j]; }
  __syncthreads();

  if (wid < 2) {
    int m = wid ? m1 : m0;
    const float* LV = wid ? lv1 : lv0;
    u32 CB = state[3 + wid];
    float part = 0.0f;
    for (int j = lane; j < m; j += 64) {
      float vj = LV[j];
      int cnt = 0;
      for (int k = 0; k < m; ++k) {
        float vk = LV[k];
        cnt += (vk < vj) || (vk == vj && k < j);
      }
      if (CB + (u32)cnt < KNNK) part += vj;
    }
    part = wave_sum(part);
    if (lane == 0) {
      float S = ((const float*)&state[9])[wid];
      r_idm[wid] = (S + part) * (1.0f / KNNK);
    }
  } else if (wid == 2) {
    u32 CB = state[5];
    int n0p = 0;
    for (int j = lane; j < mg; j += 64) {
      float vj = lgv[j];
      int cnt = 0;
      for (int k = 0; k < mg; ++k) {
        float vk = lgv[k];
        cnt += (vk < vj) || (vk == vj && k < j);
      }
      if (CB + (u32)cnt < KNNK && lgc[j] == 0u) n0p++;
    }
    n0p = wave_sum_i(n0p);
    if (lane == 0) r_n0 = (int)state[11] + n0p;
  }
  __syncthreads();
  if (t == 0) {
    float id0 = r_idm[0], id1 = r_idm[1];
    float den = fmaxf(fabsf(id0) + fabsf(id1), 1e-12f);
    out[0] = (r_n0 >= KNNK / 2) ? 0.0f : 1.0f;  // argmax, first-wins on tie
    out[1] = id0 / den;
    out[2] = id1 / den;
  }
}

extern "C" void kernel_launch(void* const* d_in, const int* in_sizes, int n_in,
                              void* d_out, int out_size, void* d_ws, size_t ws_size,
                              hipStream_t stream) {
  const float* query = (const float*)d_in[0];
  const float* anchor = (const float*)d_in[1];
  const int* label = (const int*)d_in[2];
  float* out = (float*)d_out;

  u32* w = (u32*)d_ws;
  float* kl = (float*)w;            // 131072
  u32* hist = w + 131072;           // 131072
  u32* state = w + 262144;          // 16
  float* lv0 = (float*)(w + 262160);
  float* lv1 = (float*)(w + 264208);
  float* lgv = (float*)(w + 266256);
  u32* lgc = w + 268304;

  k_kl<<<2048, 256, 0, stream>>>(anchor, query, kl, hist);
  k_h16<<<512, 256, 0, stream>>>(kl, label, hist);
  k_scan<<<1, 1024, 0, stream>>>(hist, state);
  k_collect<<<512, 256, 0, stream>>>(kl, label, state, lv0, lv1, lgv, lgc);
  k_finish<<<1, 256, 0, stream>>>(lv0, lv1, lgv, lgc, state, out);
}